// Round 1
// baseline (26650.311 us; speedup 1.0000x reference)
//
#include <hip/hip_runtime.h>

typedef unsigned short u16;
typedef short bf16x8 __attribute__((ext_vector_type(8)));
typedef float f32x4 __attribute__((ext_vector_type(4)));
typedef bf16x8 bf16x8_a __attribute__((may_alias));
typedef float f4 __attribute__((ext_vector_type(4)));
typedef f4 f4a __attribute__((may_alias));

#define MFMA16(a, b, c) __builtin_amdgcn_mfma_f32_16x16x32_bf16((a), (b), (c), 0, 0, 0)

// ---------- helpers ----------
__device__ __forceinline__ u16 f2bf_rne(float x) {
  unsigned u = __float_as_uint(x);
  u += 0x7FFFu + ((u >> 16) & 1u);
  return (u16)(u >> 16);
}
__device__ __forceinline__ short bfr(float x) {  // cheap round-half-up (hot path)
  return (short)((__float_as_uint(x) + 0x8000u) >> 16);
}
__device__ __forceinline__ float bf2f(u16 h) {
  return __uint_as_float(((unsigned)h) << 16);
}
__device__ __forceinline__ float sigmoid_(float x) { return 1.0f / (1.0f + __expf(-x)); }
__device__ __forceinline__ float tanh_(float x) {
  x = fminf(8.0f, fmaxf(-8.0f, x));
  float e = __expf(2.0f * x);
  return (e - 1.0f) / (e + 1.0f);
}
__device__ __forceinline__ bf16x8 ldb8(const u16* p) {  // 16B-aligned bf16x8 load
  return *(const bf16x8_a*)p;
}
__device__ __forceinline__ bf16x8 cvt8(const float* p) {  // 8 f32 -> bf16x8
  f4 lo = *(const f4a*)p;
  f4 hi = *(const f4a*)(p + 4);
  bf16x8 v;
  v[0] = bfr(lo[0]); v[1] = bfr(lo[1]); v[2] = bfr(lo[2]); v[3] = bfr(lo[3]);
  v[4] = bfr(hi[0]); v[5] = bfr(hi[1]); v[6] = bfr(hi[2]); v[7] = bfr(hi[3]);
  return v;
}

// ---------- transpose + f32->bf16: out[c][k] = in[k][c], R=rows(k), C=cols(c) ----------
__global__ __launch_bounds__(256) void transpose_cvt(const float* __restrict__ in,
                                                     u16* __restrict__ out, int R, int C) {
  __shared__ float tile[32][33];
  const int tx = threadIdx.x & 31, ty = threadIdx.x >> 5;
  const int c0 = blockIdx.x * 32, r0 = blockIdx.y * 32;
#pragma unroll
  for (int i = 0; i < 32; i += 8)
    tile[ty + i][tx] = in[(size_t)(r0 + ty + i) * C + (c0 + tx)];
  __syncthreads();
#pragma unroll
  for (int i = 0; i < 32; i += 8)
    out[(size_t)(c0 + ty + i) * R + (r0 + tx)] = f2bf_rne(tile[tx][ty + i]);
}

// ---------- encoder step ----------
// grid 64 WGs x 256 thr. WG owns hc0..hc0+15 (x4 gates). Waves: 2Mgrp(32b) x 2Ngrp(2 gates).
__global__ __launch_bounds__(256) void enc_step_k(
    const float* __restrict__ emb, const int* __restrict__ src, int t,
    const u16* __restrict__ hin, const u16* __restrict__ Wt,
    const float* __restrict__ bias, float* __restrict__ cst, u16* __restrict__ hout) {
  const int tid = threadIdx.x;
  const int lane = tid & 63, wv = tid >> 6;
  const int l15 = lane & 15, quad = lane >> 4, kq = quad * 8;
  const int hc0 = blockIdx.x * 16;
  const int Mb = (wv & 1) * 32;
  const int Ng = wv >> 1;

  __shared__ float glds[64][65];

  f32x4 acc[2][2] = {{{0.f, 0.f, 0.f, 0.f}, {0.f, 0.f, 0.f, 0.f}},
                     {{0.f, 0.f, 0.f, 0.f}, {0.f, 0.f, 0.f, 0.f}}};

  const u16* wr0 = Wt + (size_t)((Ng * 2 + 0) * 1024 + hc0 + l15) * 1536;
  const u16* wr1 = Wt + (size_t)((Ng * 2 + 1) * 1024 + hc0 + l15) * 1536;
  const int b0 = Mb + l15, b1 = Mb + 16 + l15;
  const float* er0 = emb + (size_t)src[b0 * 512 + t] * 512;
  const float* er1 = emb + (size_t)src[b1 * 512 + t] * 512;
  const u16* hr0 = hin + (size_t)b0 * 1024;
  const u16* hr1 = hin + (size_t)b1 * 1024;

  // x phase: k = 0..511 of z (emb f32, cvt on the fly)
#pragma unroll 4
  for (int ks = 0; ks < 16; ++ks) {
    const int k = ks * 32 + kq;
    bf16x8 a0 = cvt8(er0 + k);
    bf16x8 a1 = cvt8(er1 + k);
    bf16x8 q0 = ldb8(wr0 + k);
    bf16x8 q1 = ldb8(wr1 + k);
    acc[0][0] = MFMA16(a0, q0, acc[0][0]);
    acc[0][1] = MFMA16(a0, q1, acc[0][1]);
    acc[1][0] = MFMA16(a1, q0, acc[1][0]);
    acc[1][1] = MFMA16(a1, q1, acc[1][1]);
  }
  // h phase: k = 512..1535 of z
#pragma unroll 4
  for (int ks = 0; ks < 32; ++ks) {
    const int k = ks * 32 + kq;
    bf16x8 a0 = ldb8(hr0 + k);
    bf16x8 a1 = ldb8(hr1 + k);
    bf16x8 q0 = ldb8(wr0 + 512 + k);
    bf16x8 q1 = ldb8(wr1 + 512 + k);
    acc[0][0] = MFMA16(a0, q0, acc[0][0]);
    acc[0][1] = MFMA16(a0, q1, acc[0][1]);
    acc[1][0] = MFMA16(a1, q0, acc[1][0]);
    acc[1][1] = MFMA16(a1, q1, acc[1][1]);
  }
  // exchange: glds[c_local][b] ; c_local = g*16 + n
#pragma unroll
  for (int mt = 0; mt < 2; ++mt)
#pragma unroll
    for (int nt = 0; nt < 2; ++nt)
#pragma unroll
      for (int r = 0; r < 4; ++r)
        glds[Ng * 32 + nt * 16 + l15][Mb + mt * 16 + quad * 4 + r] = acc[mt][nt][r];
  __syncthreads();

  // cell update: thread -> (hcl = tid&15, bg = tid>>4), 4 batch rows each
  const int hcl = tid & 15, bg = tid >> 4;
  const int hc = hc0 + hcl;
  const float bi = bias[hc], bf_ = bias[1024 + hc], bgg = bias[2048 + hc], bo = bias[3072 + hc];
#pragma unroll
  for (int r = 0; r < 4; ++r) {
    const int b = bg * 4 + r;
    const float gi = glds[hcl][b] + bi;
    const float gf = glds[16 + hcl][b] + bf_;
    const float gg = glds[32 + hcl][b] + bgg;
    const float go = glds[48 + hcl][b] + bo;
    const float i_ = sigmoid_(gi), f_ = sigmoid_(gf), g_ = tanh_(gg), o_ = sigmoid_(go);
    const size_t ix = (size_t)b * 1024 + hc;
    const float cn = f_ * cst[ix] + i_ * g_;
    cst[ix] = cn;
    hout[ix] = f2bf_rne(o_ * tanh_(cn));
  }
}

// ---------- decoder step (one-hot input folded into epilogue gather) ----------
__global__ __launch_bounds__(256) void dec_step_k(
    const int* __restrict__ trg, int t,
    const u16* __restrict__ hin, const u16* __restrict__ Wt,
    const float* __restrict__ bias, float* __restrict__ cst, u16* __restrict__ hout) {
  const int tid = threadIdx.x;
  const int lane = tid & 63, wv = tid >> 6;
  const int l15 = lane & 15, quad = lane >> 4, kq = quad * 8;
  const int hc0 = blockIdx.x * 16;
  const int Mb = (wv & 1) * 32;
  const int Ng = wv >> 1;

  __shared__ float glds[64][65];

  f32x4 acc[2][2] = {{{0.f, 0.f, 0.f, 0.f}, {0.f, 0.f, 0.f, 0.f}},
                     {{0.f, 0.f, 0.f, 0.f}, {0.f, 0.f, 0.f, 0.f}}};

  const u16* wr0 = Wt + (size_t)((Ng * 2 + 0) * 1024 + hc0 + l15) * 1088;
  const u16* wr1 = Wt + (size_t)((Ng * 2 + 1) * 1024 + hc0 + l15) * 1088;
  const int b0 = Mb + l15, b1 = Mb + 16 + l15;
  const u16* hr0 = hin + (size_t)b0 * 1024;
  const u16* hr1 = hin + (size_t)b1 * 1024;

  // h part of z: W rows 64..1087
#pragma unroll 4
  for (int ks = 0; ks < 32; ++ks) {
    const int k = ks * 32 + kq;
    bf16x8 a0 = ldb8(hr0 + k);
    bf16x8 a1 = ldb8(hr1 + k);
    bf16x8 q0 = ldb8(wr0 + 64 + k);
    bf16x8 q1 = ldb8(wr1 + 64 + k);
    acc[0][0] = MFMA16(a0, q0, acc[0][0]);
    acc[0][1] = MFMA16(a0, q1, acc[0][1]);
    acc[1][0] = MFMA16(a1, q0, acc[1][0]);
    acc[1][1] = MFMA16(a1, q1, acc[1][1]);
  }
#pragma unroll
  for (int mt = 0; mt < 2; ++mt)
#pragma unroll
    for (int nt = 0; nt < 2; ++nt)
#pragma unroll
      for (int r = 0; r < 4; ++r)
        glds[Ng * 32 + nt * 16 + l15][Mb + mt * 16 + quad * 4 + r] = acc[mt][nt][r];
  __syncthreads();

  const int hcl = tid & 15, bg = tid >> 4;
  const int hc = hc0 + hcl;
  const float bi = bias[hc], bf_ = bias[1024 + hc], bgg = bias[2048 + hc], bo = bias[3072 + hc];
#pragma unroll
  for (int r = 0; r < 4; ++r) {
    const int b = bg * 4 + r;
    const int tok = trg[b * 512 + t];  // < 64; one-hot row of dec_W == Wt[c][tok]
    const float gi = glds[hcl][b] + bi + bf2f(Wt[(size_t)(hc)*1088 + tok]);
    const float gf = glds[16 + hcl][b] + bf_ + bf2f(Wt[(size_t)(1024 + hc) * 1088 + tok]);
    const float gg = glds[32 + hcl][b] + bgg + bf2f(Wt[(size_t)(2048 + hc) * 1088 + tok]);
    const float go = glds[48 + hcl][b] + bo + bf2f(Wt[(size_t)(3072 + hc) * 1088 + tok]);
    const float i_ = sigmoid_(gi), f_ = sigmoid_(gf), g_ = tanh_(gg), o_ = sigmoid_(go);
    const size_t ix = (size_t)b * 1024 + hc;
    const float cn = f_ * cst[ix] + i_ * g_;
    cst[ix] = cn;
    hout[ix] = f2bf_rne(o_ * tanh_(cn));
  }
}

// ---------- final FC over all 32768 (t,b) rows ----------
// hrows points at h_all row0 == hbuf[(t=0)+1] base - i.e. pass HB + 65536 elements.
__global__ __launch_bounds__(256) void fc_k(const u16* __restrict__ hrows,
                                            const u16* __restrict__ Wt,
                                            const float* __restrict__ fcb,
                                            float* __restrict__ out) {
  const int tid = threadIdx.x, lane = tid & 63, wv = tid >> 6;
  const int l15 = lane & 15, quad = lane >> 4, kq = quad * 8;
  const int r0 = blockIdx.x * 64 + wv * 16;
  const u16* ar = hrows + (size_t)(r0 + l15) * 1024;
  const u16* br0 = Wt + (size_t)(0 * 16 + l15) * 1024;
  const u16* br1 = Wt + (size_t)(1 * 16 + l15) * 1024;
  const u16* br2 = Wt + (size_t)(2 * 16 + l15) * 1024;
  const u16* br3 = Wt + (size_t)(3 * 16 + l15) * 1024;
  f32x4 acc[4] = {{0.f, 0.f, 0.f, 0.f}, {0.f, 0.f, 0.f, 0.f},
                  {0.f, 0.f, 0.f, 0.f}, {0.f, 0.f, 0.f, 0.f}};
#pragma unroll 4
  for (int ks = 0; ks < 32; ++ks) {
    const int k = ks * 32 + kq;
    bf16x8 a = ldb8(ar + k);
    acc[0] = MFMA16(a, ldb8(br0 + k), acc[0]);
    acc[1] = MFMA16(a, ldb8(br1 + k), acc[1]);
    acc[2] = MFMA16(a, ldb8(br2 + k), acc[2]);
    acc[3] = MFMA16(a, ldb8(br3 + k), acc[3]);
  }
#pragma unroll
  for (int nt = 0; nt < 4; ++nt) {
    const int tag = nt * 16 + l15;
    const float bb = fcb[tag];
#pragma unroll
    for (int r = 0; r < 4; ++r) {
      const int rr = r0 + quad * 4 + r;
      const int tt = rr >> 6, b = rr & 63;
      out[(size_t)b * 32768 + (size_t)tt * 64 + tag] = acc[nt][r] + bb;
    }
  }
}

// ---------- launch ----------
extern "C" void kernel_launch(void* const* d_in, const int* in_sizes, int n_in,
                              void* d_out, int out_size, void* d_ws, size_t ws_size,
                              hipStream_t stream) {
  const int* src = (const int*)d_in[0];
  const int* trg = (const int*)d_in[1];
  const float* emb = (const float*)d_in[2];
  const float* encW = (const float*)d_in[3];
  const float* encB = (const float*)d_in[4];
  const float* decW = (const float*)d_in[5];
  const float* decB = (const float*)d_in[6];
  const float* fcW = (const float*)d_in[7];
  const float* fcB = (const float*)d_in[8];
  float* out = (float*)d_out;

  // ws layout (bytes)
  const size_t OFF_WTE = 0;               // 4096*1536*2 = 12,582,912
  const size_t OFF_WTD = 12582912;        // 4096*1088*2 =  8,912,896
  const size_t OFF_WTF = 21495808;        // 64*1024*2   =    131,072
  const size_t OFF_HA = 21626880;         //               131,072
  const size_t OFF_HB2 = 21757952;        //               131,072
  const size_t OFF_C = 21889024;          // 64*1024*4   =    262,144
  const size_t OFF_HALL = 22151168;       // 513*65536*2 = 67,239,936
  const size_t NEEDED = 89391104;
  if (ws_size < NEEDED) return;  // insufficient scratch: will fail validation, but no OOB

  char* w = (char*)d_ws;
  u16* WtE = (u16*)(w + OFF_WTE);
  u16* WtD = (u16*)(w + OFF_WTD);
  u16* WtF = (u16*)(w + OFF_WTF);
  u16* hA = (u16*)(w + OFF_HA);
  u16* hB = (u16*)(w + OFF_HB2);
  float* cs = (float*)(w + OFF_C);
  u16* HB = (u16*)(w + OFF_HALL);  // hbuf[0..512][64][1024]

  hipMemsetAsync(hA, 0, 131072, stream);
  hipMemsetAsync(cs, 0, 262144, stream);

  transpose_cvt<<<dim3(128, 48), 256, 0, stream>>>(encW, WtE, 1536, 4096);
  transpose_cvt<<<dim3(128, 34), 256, 0, stream>>>(decW, WtD, 1088, 4096);
  transpose_cvt<<<dim3(2, 32), 256, 0, stream>>>(fcW, WtF, 1024, 64);

  for (int t = 0; t < 512; ++t) {
    const u16* hin = (t & 1) ? hB : hA;
    u16* hout = (t == 511) ? HB : ((t & 1) ? hA : hB);
    enc_step_k<<<64, 256, 0, stream>>>(emb, src, t, hin, WtE, encB, cs, hout);
  }
  for (int t = 0; t < 512; ++t) {
    dec_step_k<<<64, 256, 0, stream>>>(trg, t, HB + (size_t)t * 65536, WtD, decB, cs,
                                       HB + (size_t)(t + 1) * 65536);
  }
  fc_k<<<512, 256, 0, stream>>>(HB + 65536, WtF, fcB, out);
}

// Round 2
// 26553.955 us; speedup vs baseline: 1.0036x; 1.0036x over previous
//
#include <hip/hip_runtime.h>

typedef unsigned short u16;
typedef unsigned long long u64;
typedef short bf16x8 __attribute__((ext_vector_type(8)));
typedef float f32x4 __attribute__((ext_vector_type(4)));
typedef bf16x8 bf16x8_a __attribute__((may_alias));
typedef float f4 __attribute__((ext_vector_type(4)));
typedef f4 f4a __attribute__((may_alias));

#define MFMA16(a, b, c) __builtin_amdgcn_mfma_f32_16x16x32_bf16((a), (b), (c), 0, 0, 0)

#define AGLD(p) __hip_atomic_load((p), __ATOMIC_RELAXED, __HIP_MEMORY_SCOPE_AGENT)
#define AGST(p, v) __hip_atomic_store((p), (v), __ATOMIC_RELAXED, __HIP_MEMORY_SCOPE_AGENT)

// ---------- helpers ----------
__device__ __forceinline__ u16 f2bf_rne(float x) {
  unsigned u = __float_as_uint(x);
  u += 0x7FFFu + ((u >> 16) & 1u);
  return (u16)(u >> 16);
}
__device__ __forceinline__ short bfr(float x) {  // round-half-up (hot path)
  return (short)((__float_as_uint(x) + 0x8000u) >> 16);
}
__device__ __forceinline__ float bf2f(u16 h) {
  return __uint_as_float(((unsigned)h) << 16);
}
__device__ __forceinline__ float sigmoid_(float x) { return 1.0f / (1.0f + __expf(-x)); }
__device__ __forceinline__ float tanh_(float x) {
  x = fminf(8.0f, fmaxf(-8.0f, x));
  float e = __expf(2.0f * x);
  return (e - 1.0f) / (e + 1.0f);
}
__device__ __forceinline__ bf16x8 ldb8(const u16* p) { return *(const bf16x8_a*)p; }
__device__ __forceinline__ bf16x8 cvt8(const float* p) {
  f4 lo = *(const f4a*)p;
  f4 hi = *(const f4a*)(p + 4);
  bf16x8 v;
  v[0] = bfr(lo[0]); v[1] = bfr(lo[1]); v[2] = bfr(lo[2]); v[3] = bfr(lo[3]);
  v[4] = bfr(hi[0]); v[5] = bfr(hi[1]); v[6] = bfr(hi[2]); v[7] = bfr(hi[3]);
  return v;
}
union U16B {
  u64 q[2];
  bf16x8 v;
};
__device__ __forceinline__ bf16x8 mk8(u64 lo, u64 hi) {
  U16B u;
  u.q[0] = lo;
  u.q[1] = hi;
  return u.v;
}

// ---------- transpose + f32->bf16: out[c][k] = in[k][c] ----------
__global__ __launch_bounds__(256) void transpose_cvt(const float* __restrict__ in,
                                                     u16* __restrict__ out, int R, int C) {
  __shared__ float tile[32][33];
  const int tx = threadIdx.x & 31, ty = threadIdx.x >> 5;
  const int c0 = blockIdx.x * 32, r0 = blockIdx.y * 32;
#pragma unroll
  for (int i = 0; i < 32; i += 8)
    tile[ty + i][tx] = in[(size_t)(r0 + ty + i) * C + (c0 + tx)];
  __syncthreads();
#pragma unroll
  for (int i = 0; i < 32; i += 8)
    out[(size_t)(c0 + ty + i) * R + (r0 + tx)] = f2bf_rne(tile[tx][ty + i]);
}

// ==================== persistent cooperative RNN kernel ====================
// 256 WGs x 256 thr. WG wg owns h-cols hc0=wg*4 .. +3, all 4 gates (16 out cols).
// Waves M-split batch (wave v -> rows 16v..16v+15). Weights in LDS. One grid
// barrier per step. h state exchanged cross-XCD via agent-scope (sc1) ld/st.
__global__ __launch_bounds__(256) void rnn_persist(
    const float* __restrict__ emb, const int* __restrict__ src, const int* __restrict__ trg,
    const u16* __restrict__ WtE, const u16* __restrict__ WtD,
    const float* __restrict__ encB, const float* __restrict__ decB,
    u16* __restrict__ hA, u16* __restrict__ hB, u16* __restrict__ HB,
    unsigned* __restrict__ ctr) {
  constexpr int LDSP = 1544;  // 1536 + 8 pad -> 772 dwords/row, 772%32==4: conflict-free-ish
  __shared__ u16 ldsW[16 * LDSP];   // 49408 B
  __shared__ float glds[16][68];    // gate exchange
  __shared__ u16 hlds[64][4];       // h staging for vectorized store

  const int tid = threadIdx.x;
  const int lane = tid & 63, wv = tid >> 6;
  const int l15 = lane & 15, quad = lane >> 4, kq = quad * 8;
  const int Mb = wv * 16;
  const int wg = blockIdx.x;
  const int hc0 = wg * 4;
  const int eb = tid >> 2, ehc = tid & 3;  // epilogue: thread -> (batch, hc-local)
  const int arow = Mb + l15;               // this lane's batch row (A operand)

  // ---- stage encoder weights into LDS: row c=g*4+j <- WtE[g*1024+hc0+j][0..1535]
  for (int i = tid; i < 16 * 192; i += 256) {
    const int c = i / 192, ch = i % 192;
    const int g = c >> 2, j = c & 3;
    *(bf16x8_a*)&ldsW[c * LDSP + ch * 8] =
        ldb8(WtE + (size_t)(g * 1024 + hc0 + j) * 1536 + ch * 8);
  }
  float bi = encB[hc0 + ehc], bf_ = encB[1024 + hc0 + ehc],
        bg_ = encB[2048 + hc0 + ehc], bo_ = encB[3072 + hc0 + ehc];
  float cstate = 0.0f;  // c-state lives in a register for the whole kernel
  __syncthreads();

  unsigned stepno = 0;

  // ==================== encoder: 512 steps ====================
  for (int t = 0; t < 512; ++t) {
    const u16* hin = (t & 1) ? hB : hA;
    u16* hout = (t == 511) ? HB : ((t & 1) ? hA : hB);

    f32x4 ac0 = {0.f, 0.f, 0.f, 0.f}, ac1 = ac0, ac2 = ac0, ac3 = ac0;

    {  // x phase: k 0..511 (emb f32, cvt on the fly; ordinary cached loads)
      const float* er = emb + (size_t)src[arow * 512 + t] * 512 + kq;
      const u16* wl = &ldsW[l15 * LDSP + kq];
#pragma unroll
      for (int ks = 0; ks < 16; ks += 4) {
        bf16x8 a0 = cvt8(er + (ks + 0) * 32);
        bf16x8 a1 = cvt8(er + (ks + 1) * 32);
        bf16x8 a2 = cvt8(er + (ks + 2) * 32);
        bf16x8 a3 = cvt8(er + (ks + 3) * 32);
        ac0 = MFMA16(a0, ldb8(wl + (ks + 0) * 32), ac0);
        ac1 = MFMA16(a1, ldb8(wl + (ks + 1) * 32), ac1);
        ac2 = MFMA16(a2, ldb8(wl + (ks + 2) * 32), ac2);
        ac3 = MFMA16(a3, ldb8(wl + (ks + 3) * 32), ac3);
      }
    }
    {  // h phase: k 512..1535; h via agent(sc1) loads -> coherent, bypass stale L1/L2
      const u64* hr = (const u64*)(hin + (size_t)arow * 1024 + kq);
      const u16* wl = &ldsW[l15 * LDSP + 512 + kq];
#pragma unroll
      for (int ks = 0; ks < 32; ks += 4) {
        u64 q0a = AGLD(hr + (ks + 0) * 8), q0b = AGLD(hr + (ks + 0) * 8 + 1);
        u64 q1a = AGLD(hr + (ks + 1) * 8), q1b = AGLD(hr + (ks + 1) * 8 + 1);
        u64 q2a = AGLD(hr + (ks + 2) * 8), q2b = AGLD(hr + (ks + 2) * 8 + 1);
        u64 q3a = AGLD(hr + (ks + 3) * 8), q3b = AGLD(hr + (ks + 3) * 8 + 1);
        ac0 = MFMA16(mk8(q0a, q0b), ldb8(wl + (ks + 0) * 32), ac0);
        ac1 = MFMA16(mk8(q1a, q1b), ldb8(wl + (ks + 1) * 32), ac1);
        ac2 = MFMA16(mk8(q2a, q2b), ldb8(wl + (ks + 2) * 32), ac2);
        ac3 = MFMA16(mk8(q3a, q3b), ldb8(wl + (ks + 3) * 32), ac3);
      }
    }
    f32x4 acc = (ac0 + ac1) + (ac2 + ac3);
#pragma unroll
    for (int r = 0; r < 4; ++r) glds[l15][Mb + quad * 4 + r] = acc[r];
    __syncthreads();

    // epilogue: thread (eb, ehc) does one LSTM cell
    {
      const float gi = glds[ehc][eb] + bi;
      const float gf = glds[4 + ehc][eb] + bf_;
      const float gg = glds[8 + ehc][eb] + bg_;
      const float go = glds[12 + ehc][eb] + bo_;
      const float iv = sigmoid_(gi), fv = sigmoid_(gf), gv = tanh_(gg), ov = sigmoid_(go);
      cstate = fv * cstate + iv * gv;
      hlds[eb][ehc] = f2bf_rne(ov * tanh_(cstate));
    }
    __syncthreads();
    if (tid < 64)
      AGST((u64*)(hout + (size_t)tid * 1024 + hc0), *(const u64*)&hlds[tid][0]);

    // grid barrier
    ++stepno;
    __builtin_amdgcn_fence(__ATOMIC_RELEASE, "agent");  // drain h stores (L2 nearly clean)
    __syncthreads();
    if (tid == 0) {
      atomicAdd(ctr, 1u);
      const unsigned tgt = 256u * stepno;
      while (AGLD(ctr) < tgt) __builtin_amdgcn_s_sleep(2);
    }
    __syncthreads();
    __builtin_amdgcn_fence(__ATOMIC_ACQUIRE, "workgroup");  // cheap compiler ordering
  }

  // ---- swap to decoder weights + biases
  for (int i = tid; i < 16 * 136; i += 256) {
    const int c = i / 136, ch = i % 136;
    const int g = c >> 2, j = c & 3;
    *(bf16x8_a*)&ldsW[c * LDSP + ch * 8] =
        ldb8(WtD + (size_t)(g * 1024 + hc0 + j) * 1088 + ch * 8);
  }
  bi = decB[hc0 + ehc]; bf_ = decB[1024 + hc0 + ehc];
  bg_ = decB[2048 + hc0 + ehc]; bo_ = decB[3072 + hc0 + ehc];
  __syncthreads();

  // ==================== decoder: 512 steps ====================
  for (int t = 0; t < 512; ++t) {
    const u16* hin = HB + (size_t)t * 65536;
    u16* hout = HB + (size_t)(t + 1) * 65536;

    f32x4 ac0 = {0.f, 0.f, 0.f, 0.f}, ac1 = ac0, ac2 = ac0, ac3 = ac0;
    {  // h phase only: z rows 64..1087 of dec_W
      const u64* hr = (const u64*)(hin + (size_t)arow * 1024 + kq);
      const u16* wl = &ldsW[l15 * LDSP + 64 + kq];
#pragma unroll
      for (int ks = 0; ks < 32; ks += 4) {
        u64 q0a = AGLD(hr + (ks + 0) * 8), q0b = AGLD(hr + (ks + 0) * 8 + 1);
        u64 q1a = AGLD(hr + (ks + 1) * 8), q1b = AGLD(hr + (ks + 1) * 8 + 1);
        u64 q2a = AGLD(hr + (ks + 2) * 8), q2b = AGLD(hr + (ks + 2) * 8 + 1);
        u64 q3a = AGLD(hr + (ks + 3) * 8), q3b = AGLD(hr + (ks + 3) * 8 + 1);
        ac0 = MFMA16(mk8(q0a, q0b), ldb8(wl + (ks + 0) * 32), ac0);
        ac1 = MFMA16(mk8(q1a, q1b), ldb8(wl + (ks + 1) * 32), ac1);
        ac2 = MFMA16(mk8(q2a, q2b), ldb8(wl + (ks + 2) * 32), ac2);
        ac3 = MFMA16(mk8(q3a, q3b), ldb8(wl + (ks + 3) * 32), ac3);
      }
    }
    f32x4 acc = (ac0 + ac1) + (ac2 + ac3);
#pragma unroll
    for (int r = 0; r < 4; ++r) glds[l15][Mb + quad * 4 + r] = acc[r];
    __syncthreads();

    {  // epilogue + one-hot gather from LDS weights (z row = trg token)
      const int tok = trg[eb * 512 + t];
      const float gi = glds[ehc][eb] + bi + bf2f(ldsW[(0 + ehc) * LDSP + tok]);
      const float gf = glds[4 + ehc][eb] + bf_ + bf2f(ldsW[(4 + ehc) * LDSP + tok]);
      const float gg = glds[8 + ehc][eb] + bg_ + bf2f(ldsW[(8 + ehc) * LDSP + tok]);
      const float go = glds[12 + ehc][eb] + bo_ + bf2f(ldsW[(12 + ehc) * LDSP + tok]);
      const float iv = sigmoid_(gi), fv = sigmoid_(gf), gv = tanh_(gg), ov = sigmoid_(go);
      cstate = fv * cstate + iv * gv;
      hlds[eb][ehc] = f2bf_rne(ov * tanh_(cstate));
    }
    __syncthreads();
    if (tid < 64)
      AGST((u64*)(hout + (size_t)tid * 1024 + hc0), *(const u64*)&hlds[tid][0]);

    ++stepno;
    __builtin_amdgcn_fence(__ATOMIC_RELEASE, "agent");
    __syncthreads();
    if (tid == 0) {
      atomicAdd(ctr, 1u);
      const unsigned tgt = 256u * stepno;
      while (AGLD(ctr) < tgt) __builtin_amdgcn_s_sleep(2);
    }
    __syncthreads();
    __builtin_amdgcn_fence(__ATOMIC_ACQUIRE, "workgroup");
  }
}

// ==================== round-1 per-step kernels (fallback path) ====================
__global__ __launch_bounds__(256) void enc_step_k(
    const float* __restrict__ emb, const int* __restrict__ src, int t,
    const u16* __restrict__ hin, const u16* __restrict__ Wt,
    const float* __restrict__ bias, float* __restrict__ cst, u16* __restrict__ hout) {
  const int tid = threadIdx.x;
  const int lane = tid & 63, wv = tid >> 6;
  const int l15 = lane & 15, quad = lane >> 4, kq = quad * 8;
  const int hc0 = blockIdx.x * 16;
  const int Mb = (wv & 1) * 32;
  const int Ng = wv >> 1;
  __shared__ float glds[64][65];
  f32x4 acc[2][2] = {{{0.f, 0.f, 0.f, 0.f}, {0.f, 0.f, 0.f, 0.f}},
                     {{0.f, 0.f, 0.f, 0.f}, {0.f, 0.f, 0.f, 0.f}}};
  const u16* wr0 = Wt + (size_t)((Ng * 2 + 0) * 1024 + hc0 + l15) * 1536;
  const u16* wr1 = Wt + (size_t)((Ng * 2 + 1) * 1024 + hc0 + l15) * 1536;
  const int b0 = Mb + l15, b1 = Mb + 16 + l15;
  const float* er0 = emb + (size_t)src[b0 * 512 + t] * 512;
  const float* er1 = emb + (size_t)src[b1 * 512 + t] * 512;
  const u16* hr0 = hin + (size_t)b0 * 1024;
  const u16* hr1 = hin + (size_t)b1 * 1024;
#pragma unroll 4
  for (int ks = 0; ks < 16; ++ks) {
    const int k = ks * 32 + kq;
    bf16x8 a0 = cvt8(er0 + k), a1 = cvt8(er1 + k);
    bf16x8 q0 = ldb8(wr0 + k), q1 = ldb8(wr1 + k);
    acc[0][0] = MFMA16(a0, q0, acc[0][0]);
    acc[0][1] = MFMA16(a0, q1, acc[0][1]);
    acc[1][0] = MFMA16(a1, q0, acc[1][0]);
    acc[1][1] = MFMA16(a1, q1, acc[1][1]);
  }
#pragma unroll 4
  for (int ks = 0; ks < 32; ++ks) {
    const int k = ks * 32 + kq;
    bf16x8 a0 = ldb8(hr0 + k), a1 = ldb8(hr1 + k);
    bf16x8 q0 = ldb8(wr0 + 512 + k), q1 = ldb8(wr1 + 512 + k);
    acc[0][0] = MFMA16(a0, q0, acc[0][0]);
    acc[0][1] = MFMA16(a0, q1, acc[0][1]);
    acc[1][0] = MFMA16(a1, q0, acc[1][0]);
    acc[1][1] = MFMA16(a1, q1, acc[1][1]);
  }
#pragma unroll
  for (int mt = 0; mt < 2; ++mt)
#pragma unroll
    for (int nt = 0; nt < 2; ++nt)
#pragma unroll
      for (int r = 0; r < 4; ++r)
        glds[Ng * 32 + nt * 16 + l15][Mb + mt * 16 + quad * 4 + r] = acc[mt][nt][r];
  __syncthreads();
  const int hcl = tid & 15, bg = tid >> 4;
  const int hc = hc0 + hcl;
  const float bi = bias[hc], bf_ = bias[1024 + hc], bgg = bias[2048 + hc], bo = bias[3072 + hc];
#pragma unroll
  for (int r = 0; r < 4; ++r) {
    const int b = bg * 4 + r;
    const float gi = glds[hcl][b] + bi;
    const float gf = glds[16 + hcl][b] + bf_;
    const float gg = glds[32 + hcl][b] + bgg;
    const float go = glds[48 + hcl][b] + bo;
    const float i_ = sigmoid_(gi), f_ = sigmoid_(gf), g_ = tanh_(gg), o_ = sigmoid_(go);
    const size_t ix = (size_t)b * 1024 + hc;
    const float cn = f_ * cst[ix] + i_ * g_;
    cst[ix] = cn;
    hout[ix] = f2bf_rne(o_ * tanh_(cn));
  }
}

__global__ __launch_bounds__(256) void dec_step_k(
    const int* __restrict__ trg, int t,
    const u16* __restrict__ hin, const u16* __restrict__ Wt,
    const float* __restrict__ bias, float* __restrict__ cst, u16* __restrict__ hout) {
  const int tid = threadIdx.x;
  const int lane = tid & 63, wv = tid >> 6;
  const int l15 = lane & 15, quad = lane >> 4, kq = quad * 8;
  const int hc0 = blockIdx.x * 16;
  const int Mb = (wv & 1) * 32;
  const int Ng = wv >> 1;
  __shared__ float glds[64][65];
  f32x4 acc[2][2] = {{{0.f, 0.f, 0.f, 0.f}, {0.f, 0.f, 0.f, 0.f}},
                     {{0.f, 0.f, 0.f, 0.f}, {0.f, 0.f, 0.f, 0.f}}};
  const u16* wr0 = Wt + (size_t)((Ng * 2 + 0) * 1024 + hc0 + l15) * 1088;
  const u16* wr1 = Wt + (size_t)((Ng * 2 + 1) * 1024 + hc0 + l15) * 1088;
  const int b0 = Mb + l15, b1 = Mb + 16 + l15;
  const u16* hr0 = hin + (size_t)b0 * 1024;
  const u16* hr1 = hin + (size_t)b1 * 1024;
#pragma unroll 4
  for (int ks = 0; ks < 32; ++ks) {
    const int k = ks * 32 + kq;
    bf16x8 a0 = ldb8(hr0 + k), a1 = ldb8(hr1 + k);
    bf16x8 q0 = ldb8(wr0 + 64 + k), q1 = ldb8(wr1 + 64 + k);
    acc[0][0] = MFMA16(a0, q0, acc[0][0]);
    acc[0][1] = MFMA16(a0, q1, acc[0][1]);
    acc[1][0] = MFMA16(a1, q0, acc[1][0]);
    acc[1][1] = MFMA16(a1, q1, acc[1][1]);
  }
#pragma unroll
  for (int mt = 0; mt < 2; ++mt)
#pragma unroll
    for (int nt = 0; nt < 2; ++nt)
#pragma unroll
      for (int r = 0; r < 4; ++r)
        glds[Ng * 32 + nt * 16 + l15][Mb + mt * 16 + quad * 4 + r] = acc[mt][nt][r];
  __syncthreads();
  const int hcl = tid & 15, bg = tid >> 4;
  const int hc = hc0 + hcl;
  const float bi = bias[hc], bf_ = bias[1024 + hc], bgg = bias[2048 + hc], bo = bias[3072 + hc];
#pragma unroll
  for (int r = 0; r < 4; ++r) {
    const int b = bg * 4 + r;
    const int tok = trg[b * 512 + t];
    const float gi = glds[hcl][b] + bi + bf2f(Wt[(size_t)(hc)*1088 + tok]);
    const float gf = glds[16 + hcl][b] + bf_ + bf2f(Wt[(size_t)(1024 + hc) * 1088 + tok]);
    const float gg = glds[32 + hcl][b] + bgg + bf2f(Wt[(size_t)(2048 + hc) * 1088 + tok]);
    const float go = glds[48 + hcl][b] + bo + bf2f(Wt[(size_t)(3072 + hc) * 1088 + tok]);
    const float i_ = sigmoid_(gi), f_ = sigmoid_(gf), g_ = tanh_(gg), o_ = sigmoid_(go);
    const size_t ix = (size_t)b * 1024 + hc;
    const float cn = f_ * cst[ix] + i_ * g_;
    cst[ix] = cn;
    hout[ix] = f2bf_rne(o_ * tanh_(cn));
  }
}

// ---------- final FC over all 32768 (t,b) rows ----------
__global__ __launch_bounds__(256) void fc_k(const u16* __restrict__ hrows,
                                            const u16* __restrict__ Wt,
                                            const float* __restrict__ fcb,
                                            float* __restrict__ out) {
  const int tid = threadIdx.x, lane = tid & 63, wv = tid >> 6;
  const int l15 = lane & 15, quad = lane >> 4, kq = quad * 8;
  const int r0 = blockIdx.x * 64 + wv * 16;
  const u16* ar = hrows + (size_t)(r0 + l15) * 1024;
  const u16* br0 = Wt + (size_t)(0 * 16 + l15) * 1024;
  const u16* br1 = Wt + (size_t)(1 * 16 + l15) * 1024;
  const u16* br2 = Wt + (size_t)(2 * 16 + l15) * 1024;
  const u16* br3 = Wt + (size_t)(3 * 16 + l15) * 1024;
  f32x4 acc[4] = {{0.f, 0.f, 0.f, 0.f}, {0.f, 0.f, 0.f, 0.f},
                  {0.f, 0.f, 0.f, 0.f}, {0.f, 0.f, 0.f, 0.f}};
#pragma unroll 4
  for (int ks = 0; ks < 32; ++ks) {
    const int k = ks * 32 + kq;
    bf16x8 a = ldb8(ar + k);
    acc[0] = MFMA16(a, ldb8(br0 + k), acc[0]);
    acc[1] = MFMA16(a, ldb8(br1 + k), acc[1]);
    acc[2] = MFMA16(a, ldb8(br2 + k), acc[2]);
    acc[3] = MFMA16(a, ldb8(br3 + k), acc[3]);
  }
#pragma unroll
  for (int nt = 0; nt < 4; ++nt) {
    const int tag = nt * 16 + l15;
    const float bb = fcb[tag];
#pragma unroll
    for (int r = 0; r < 4; ++r) {
      const int rr = r0 + quad * 4 + r;
      const int tt = rr >> 6, b = rr & 63;
      out[(size_t)b * 32768 + (size_t)tt * 64 + tag] = acc[nt][r] + bb;
    }
  }
}

// ---------- launch ----------
extern "C" void kernel_launch(void* const* d_in, const int* in_sizes, int n_in,
                              void* d_out, int out_size, void* d_ws, size_t ws_size,
                              hipStream_t stream) {
  const int* src = (const int*)d_in[0];
  const int* trg = (const int*)d_in[1];
  const float* emb = (const float*)d_in[2];
  const float* encW = (const float*)d_in[3];
  const float* encB = (const float*)d_in[4];
  const float* decW = (const float*)d_in[5];
  const float* decB = (const float*)d_in[6];
  const float* fcW = (const float*)d_in[7];
  const float* fcB = (const float*)d_in[8];
  float* out = (float*)d_out;

  // ws layout — identical to round 1 (proven to fit)
  const size_t OFF_WTE = 0;          // 12,582,912
  const size_t OFF_WTD = 12582912;   //  8,912,896
  const size_t OFF_WTF = 21495808;   //    131,072
  const size_t OFF_HA = 21626880;    //    131,072
  const size_t OFF_HB2 = 21757952;   //    131,072
  const size_t OFF_C = 21889024;     //    262,144 (ctr | fallback c-state)
  const size_t OFF_HALL = 22151168;  // 67,239,936
  const size_t NEEDED = 89391104;
  if (ws_size < NEEDED) return;

  char* w = (char*)d_ws;
  u16* WtE = (u16*)(w + OFF_WTE);
  u16* WtD = (u16*)(w + OFF_WTD);
  u16* WtF = (u16*)(w + OFF_WTF);
  u16* hA = (u16*)(w + OFF_HA);
  u16* hB = (u16*)(w + OFF_HB2);
  unsigned* ctr = (unsigned*)(w + OFF_C);
  float* cs = (float*)(w + OFF_C);  // fallback only (aliases ctr; paths are exclusive)
  u16* HB = (u16*)(w + OFF_HALL);

  hipMemsetAsync(hA, 0, 131072, stream);
  hipMemsetAsync((void*)ctr, 0, 262144, stream);  // ctr=0 (also zeroes fallback c-state)

  transpose_cvt<<<dim3(128, 48), 256, 0, stream>>>(encW, WtE, 1536, 4096);
  transpose_cvt<<<dim3(128, 34), 256, 0, stream>>>(decW, WtD, 1088, 4096);
  transpose_cvt<<<dim3(2, 32), 256, 0, stream>>>(fcW, WtF, 1024, 64);

  void* args[] = {(void*)&emb, (void*)&src, (void*)&trg, (void*)&WtE, (void*)&WtD,
                  (void*)&encB, (void*)&decB, (void*)&hA, (void*)&hB, (void*)&HB,
                  (void*)&ctr};
  hipError_t e = hipLaunchCooperativeKernel((const void*)rnn_persist, dim3(256), dim3(256),
                                            args, 0, stream);
  if (e != hipSuccess) {
    // fallback: proven round-1 per-step path
    for (int t = 0; t < 512; ++t) {
      const u16* hin = (t & 1) ? hB : hA;
      u16* hout = (t == 511) ? HB : ((t & 1) ? hA : hB);
      enc_step_k<<<64, 256, 0, stream>>>(emb, src, t, hin, WtE, encB, cs, hout);
    }
    for (int t = 0; t < 512; ++t) {
      dec_step_k<<<64, 256, 0, stream>>>(trg, t, HB + (size_t)t * 65536, WtD, decB, cs,
                                         HB + (size_t)(t + 1) * 65536);
    }
  }
  fc_k<<<512, 256, 0, stream>>>(HB + 65536, WtF, fcB, out);
}

// Round 3
// 15290.086 us; speedup vs baseline: 1.7430x; 1.7367x over previous
//
#include <hip/hip_runtime.h>

typedef unsigned short u16;
typedef unsigned long long u64;
typedef short bf16x8 __attribute__((ext_vector_type(8)));
typedef float f32x4 __attribute__((ext_vector_type(4)));
typedef bf16x8 bf16x8_a __attribute__((may_alias));
typedef float f4 __attribute__((ext_vector_type(4)));
typedef f4 f4a __attribute__((may_alias));

#define MFMA16(a, b, c) __builtin_amdgcn_mfma_f32_16x16x32_bf16((a), (b), (c), 0, 0, 0)

#define AGLD(p) __hip_atomic_load((p), __ATOMIC_RELAXED, __HIP_MEMORY_SCOPE_AGENT)
#define AGST(p, v) __hip_atomic_store((p), (v), __ATOMIC_RELAXED, __HIP_MEMORY_SCOPE_AGENT)

// ---------- helpers ----------
__device__ __forceinline__ u16 f2bf_rne(float x) {
  unsigned u = __float_as_uint(x);
  u += 0x7FFFu + ((u >> 16) & 1u);
  return (u16)(u >> 16);
}
__device__ __forceinline__ short bfr(float x) {  // round-half-up (hot path)
  return (short)((__float_as_uint(x) + 0x8000u) >> 16);
}
__device__ __forceinline__ float bf2f(u16 h) {
  return __uint_as_float(((unsigned)h) << 16);
}
__device__ __forceinline__ float sigmoid_(float x) { return 1.0f / (1.0f + __expf(-x)); }
__device__ __forceinline__ float tanh_(float x) {
  x = fminf(8.0f, fmaxf(-8.0f, x));
  float e = __expf(2.0f * x);
  return (e - 1.0f) / (e + 1.0f);
}
__device__ __forceinline__ bf16x8 ldb8(const u16* p) { return *(const bf16x8_a*)p; }
__device__ __forceinline__ bf16x8 cvt8(const float* p) {
  f4 lo = *(const f4a*)p;
  f4 hi = *(const f4a*)(p + 4);
  bf16x8 v;
  v[0] = bfr(lo[0]); v[1] = bfr(lo[1]); v[2] = bfr(lo[2]); v[3] = bfr(lo[3]);
  v[4] = bfr(hi[0]); v[5] = bfr(hi[1]); v[6] = bfr(hi[2]); v[7] = bfr(hi[3]);
  return v;
}
union U16B {
  u64 q[2];
  bf16x8 v;
};
__device__ __forceinline__ bf16x8 mk8(u64 lo, u64 hi) {
  U16B u;
  u.q[0] = lo;
  u.q[1] = hi;
  return u.v;
}

// ---------- transpose + f32->bf16: out[c][k] = in[k][c] ----------
__global__ __launch_bounds__(256) void transpose_cvt(const float* __restrict__ in,
                                                     u16* __restrict__ out, int R, int C) {
  __shared__ float tile[32][33];
  const int tx = threadIdx.x & 31, ty = threadIdx.x >> 5;
  const int c0 = blockIdx.x * 32, r0 = blockIdx.y * 32;
#pragma unroll
  for (int i = 0; i < 32; i += 8)
    tile[ty + i][tx] = in[(size_t)(r0 + ty + i) * C + (c0 + tx)];
  __syncthreads();
#pragma unroll
  for (int i = 0; i < 32; i += 8)
    out[(size_t)(c0 + ty + i) * R + (r0 + tx)] = f2bf_rne(tile[tx][ty + i]);
}

// ==================== persistent cooperative RNN kernel ====================
// 256 WGs x 256 thr. WG owns h-cols hc0=wg*4..+3, all 4 gates (16 out cols).
// Waves M-split batch. Weights in LDS. Per-step grid sync via per-WG epoch
// flags (contention-free: 256 parallel release-stores + distributed poll).
__global__ __launch_bounds__(256, 1) void rnn_persist(
    const float* __restrict__ emb, const int* __restrict__ src, const int* __restrict__ trg,
    const u16* __restrict__ WtE, const u16* __restrict__ WtD,
    const float* __restrict__ encB, const float* __restrict__ decB,
    u16* __restrict__ hA, u16* __restrict__ hB, u16* __restrict__ HB,
    unsigned* __restrict__ flags) {
  constexpr int LDSP = 1544;
  __shared__ u16 ldsW[16 * LDSP];  // 49.4 KB
  __shared__ float glds[16][68];
  __shared__ u16 hlds[64][4];

  const int tid = threadIdx.x;
  const int lane = tid & 63, wv = tid >> 6;
  const int l15 = lane & 15, quad = lane >> 4, kq = quad * 8;
  const int Mb = wv * 16;
  const int wg = blockIdx.x;
  const int hc0 = wg * 4;
  const int eb = tid >> 2, ehc = tid & 3;
  const int arow = Mb + l15;

  // stage encoder weights: LDS row c=g*4+j <- WtE col g*1024+hc0+j
  for (int i = tid; i < 16 * 192; i += 256) {
    const int c = i / 192, ch = i % 192;
    const int g = c >> 2, j = c & 3;
    *(bf16x8_a*)&ldsW[c * LDSP + ch * 8] =
        ldb8(WtE + (size_t)(g * 1024 + hc0 + j) * 1536 + ch * 8);
  }
  float bi = encB[hc0 + ehc], bf_ = encB[1024 + hc0 + ehc],
        bg_ = encB[2048 + hc0 + ehc], bo_ = encB[3072 + hc0 + ehc];
  float cstate = 0.0f;
  __syncthreads();

  f32x4 acc[4];
  acc[0] = (f32x4){0.f, 0.f, 0.f, 0.f};
  acc[1] = acc[0]; acc[2] = acc[0]; acc[3] = acc[0];
  {  // x_gemm(t=0) prologue
    const float* er = emb + (size_t)src[arow * 512 + 0] * 512 + kq;
    const u16* wx = &ldsW[l15 * LDSP + kq];
#pragma unroll
    for (int i = 0; i < 16; ++i)
      acc[i & 3] = MFMA16(cvt8(er + i * 32), ldb8(wx + i * 32), acc[i & 3]);
  }

  // ==================== encoder: 512 steps ====================
  for (int t = 0; t < 512; ++t) {
    // ---- wait: h[t] ready (epoch t); each thread polls one WG's flag
    const unsigned ep = (unsigned)t;
    while (AGLD(&flags[tid]) < ep) __builtin_amdgcn_s_sleep(1);
    __syncthreads();
    __builtin_amdgcn_fence(__ATOMIC_ACQUIRE, "workgroup");

    const u16* hin = (t & 1) ? hB : hA;
    u16* hout = (t == 511) ? HB : ((t & 1) ? hA : hB);

    // ---- prefetch ALL h A-fragments (64 AGLD in flight), then MFMA
    const u64* hr = (const u64*)(hin + (size_t)arow * 1024 + kq);
    u64 qa[64];
#pragma unroll
    for (int i = 0; i < 32; ++i) {
      qa[2 * i] = AGLD(hr + i * 8);
      qa[2 * i + 1] = AGLD(hr + i * 8 + 1);
    }
    const u16* wl = &ldsW[l15 * LDSP + 512 + kq];
#pragma unroll
    for (int i = 0; i < 32; ++i)
      acc[i & 3] = MFMA16(mk8(qa[2 * i], qa[2 * i + 1]), ldb8(wl + i * 32), acc[i & 3]);

    f32x4 asum = (acc[0] + acc[1]) + (acc[2] + acc[3]);
#pragma unroll
    for (int r = 0; r < 4; ++r) glds[l15][Mb + quad * 4 + r] = asum[r];
    __syncthreads();

    {  // LSTM cell: thread -> (eb, ehc)
      const float gi = glds[ehc][eb] + bi;
      const float gf = glds[4 + ehc][eb] + bf_;
      const float gg = glds[8 + ehc][eb] + bg_;
      const float go = glds[12 + ehc][eb] + bo_;
      const float iv = sigmoid_(gi), fv = sigmoid_(gf), gv = tanh_(gg), ov = sigmoid_(go);
      cstate = fv * cstate + iv * gv;
      hlds[eb][ehc] = f2bf_rne(ov * tanh_(cstate));
    }
    __syncthreads();
    if (tid < 64)
      AGST((u64*)(hout + (size_t)tid * 1024 + hc0), *(const u64*)&hlds[tid][0]);
    if (tid == 0)
      __hip_atomic_store(&flags[wg], (unsigned)(t + 1), __ATOMIC_RELEASE,
                         __HIP_MEMORY_SCOPE_AGENT);

    // ---- overlap barrier window with next step's x-phase (no h dependency)
    acc[0] = (f32x4){0.f, 0.f, 0.f, 0.f};
    acc[1] = acc[0]; acc[2] = acc[0]; acc[3] = acc[0];
    if (t < 511) {
      const float* er = emb + (size_t)src[arow * 512 + (t + 1)] * 512 + kq;
      const u16* wx = &ldsW[l15 * LDSP + kq];
#pragma unroll
      for (int i = 0; i < 16; ++i)
        acc[i & 3] = MFMA16(cvt8(er + i * 32), ldb8(wx + i * 32), acc[i & 3]);
    }
  }

  // ---- swap to decoder weights + biases (safe: all ldsW reads done; LDS is WG-private)
  for (int i = tid; i < 16 * 136; i += 256) {
    const int c = i / 136, ch = i % 136;
    const int g = c >> 2, j = c & 3;
    *(bf16x8_a*)&ldsW[c * LDSP + ch * 8] =
        ldb8(WtD + (size_t)(g * 1024 + hc0 + j) * 1088 + ch * 8);
  }
  bi = decB[hc0 + ehc]; bf_ = decB[1024 + hc0 + ehc];
  bg_ = decB[2048 + hc0 + ehc]; bo_ = decB[3072 + hc0 + ehc];
  __syncthreads();

  // ==================== decoder: 512 steps ====================
  for (int t = 0; t < 512; ++t) {
    const unsigned ep = (unsigned)(512 + t);
    while (AGLD(&flags[tid]) < ep) __builtin_amdgcn_s_sleep(1);
    __syncthreads();
    __builtin_amdgcn_fence(__ATOMIC_ACQUIRE, "workgroup");

    const u16* hin = HB + (size_t)t * 65536;
    u16* hout = HB + (size_t)(t + 1) * 65536;

    const u64* hr = (const u64*)(hin + (size_t)arow * 1024 + kq);
    u64 qa[64];
#pragma unroll
    for (int i = 0; i < 32; ++i) {
      qa[2 * i] = AGLD(hr + i * 8);
      qa[2 * i + 1] = AGLD(hr + i * 8 + 1);
    }
    acc[0] = (f32x4){0.f, 0.f, 0.f, 0.f};
    acc[1] = acc[0]; acc[2] = acc[0]; acc[3] = acc[0];
    const u16* wl = &ldsW[l15 * LDSP + 64 + kq];
#pragma unroll
    for (int i = 0; i < 32; ++i)
      acc[i & 3] = MFMA16(mk8(qa[2 * i], qa[2 * i + 1]), ldb8(wl + i * 32), acc[i & 3]);

    f32x4 asum = (acc[0] + acc[1]) + (acc[2] + acc[3]);
#pragma unroll
    for (int r = 0; r < 4; ++r) glds[l15][Mb + quad * 4 + r] = asum[r];
    __syncthreads();

    {  // cell + one-hot gather from LDS weights (z row = trg token)
      const int tok = trg[eb * 512 + t];
      const float gi = glds[ehc][eb] + bi + bf2f(ldsW[(0 + ehc) * LDSP + tok]);
      const float gf = glds[4 + ehc][eb] + bf_ + bf2f(ldsW[(4 + ehc) * LDSP + tok]);
      const float gg = glds[8 + ehc][eb] + bg_ + bf2f(ldsW[(8 + ehc) * LDSP + tok]);
      const float go = glds[12 + ehc][eb] + bo_ + bf2f(ldsW[(12 + ehc) * LDSP + tok]);
      const float iv = sigmoid_(gi), fv = sigmoid_(gf), gv = tanh_(gg), ov = sigmoid_(go);
      cstate = fv * cstate + iv * gv;
      hlds[eb][ehc] = f2bf_rne(ov * tanh_(cstate));
    }
    __syncthreads();
    if (tid < 64)
      AGST((u64*)(hout + (size_t)tid * 1024 + hc0), *(const u64*)&hlds[tid][0]);
    if (tid == 0)
      __hip_atomic_store(&flags[wg], (unsigned)(512 + t + 1), __ATOMIC_RELEASE,
                         __HIP_MEMORY_SCOPE_AGENT);
  }
}

// ==================== round-1 per-step kernels (fallback path) ====================
__global__ __launch_bounds__(256) void enc_step_k(
    const float* __restrict__ emb, const int* __restrict__ src, int t,
    const u16* __restrict__ hin, const u16* __restrict__ Wt,
    const float* __restrict__ bias, float* __restrict__ cst, u16* __restrict__ hout) {
  const int tid = threadIdx.x;
  const int lane = tid & 63, wv = tid >> 6;
  const int l15 = lane & 15, quad = lane >> 4, kq = quad * 8;
  const int hc0 = blockIdx.x * 16;
  const int Mb = (wv & 1) * 32;
  const int Ng = wv >> 1;
  __shared__ float glds[64][65];
  f32x4 acc[2][2] = {{{0.f, 0.f, 0.f, 0.f}, {0.f, 0.f, 0.f, 0.f}},
                     {{0.f, 0.f, 0.f, 0.f}, {0.f, 0.f, 0.f, 0.f}}};
  const u16* wr0 = Wt + (size_t)((Ng * 2 + 0) * 1024 + hc0 + l15) * 1536;
  const u16* wr1 = Wt + (size_t)((Ng * 2 + 1) * 1024 + hc0 + l15) * 1536;
  const int b0 = Mb + l15, b1 = Mb + 16 + l15;
  const float* er0 = emb + (size_t)src[b0 * 512 + t] * 512;
  const float* er1 = emb + (size_t)src[b1 * 512 + t] * 512;
  const u16* hr0 = hin + (size_t)b0 * 1024;
  const u16* hr1 = hin + (size_t)b1 * 1024;
#pragma unroll 4
  for (int ks = 0; ks < 16; ++ks) {
    const int k = ks * 32 + kq;
    bf16x8 a0 = cvt8(er0 + k), a1 = cvt8(er1 + k);
    bf16x8 q0 = ldb8(wr0 + k), q1 = ldb8(wr1 + k);
    acc[0][0] = MFMA16(a0, q0, acc[0][0]);
    acc[0][1] = MFMA16(a0, q1, acc[0][1]);
    acc[1][0] = MFMA16(a1, q0, acc[1][0]);
    acc[1][1] = MFMA16(a1, q1, acc[1][1]);
  }
#pragma unroll 4
  for (int ks = 0; ks < 32; ++ks) {
    const int k = ks * 32 + kq;
    bf16x8 a0 = ldb8(hr0 + k), a1 = ldb8(hr1 + k);
    bf16x8 q0 = ldb8(wr0 + 512 + k), q1 = ldb8(wr1 + 512 + k);
    acc[0][0] = MFMA16(a0, q0, acc[0][0]);
    acc[0][1] = MFMA16(a0, q1, acc[0][1]);
    acc[1][0] = MFMA16(a1, q0, acc[1][0]);
    acc[1][1] = MFMA16(a1, q1, acc[1][1]);
  }
#pragma unroll
  for (int mt = 0; mt < 2; ++mt)
#pragma unroll
    for (int nt = 0; nt < 2; ++nt)
#pragma unroll
      for (int r = 0; r < 4; ++r)
        glds[Ng * 32 + nt * 16 + l15][Mb + mt * 16 + quad * 4 + r] = acc[mt][nt][r];
  __syncthreads();
  const int hcl = tid & 15, bg = tid >> 4;
  const int hc = hc0 + hcl;
  const float bi = bias[hc], bf_ = bias[1024 + hc], bgg = bias[2048 + hc], bo = bias[3072 + hc];
#pragma unroll
  for (int r = 0; r < 4; ++r) {
    const int b = bg * 4 + r;
    const float gi = glds[hcl][b] + bi;
    const float gf = glds[16 + hcl][b] + bf_;
    const float gg = glds[32 + hcl][b] + bgg;
    const float go = glds[48 + hcl][b] + bo;
    const float i_ = sigmoid_(gi), f_ = sigmoid_(gf), g_ = tanh_(gg), o_ = sigmoid_(go);
    const size_t ix = (size_t)b * 1024 + hc;
    const float cn = f_ * cst[ix] + i_ * g_;
    cst[ix] = cn;
    hout[ix] = f2bf_rne(o_ * tanh_(cn));
  }
}

__global__ __launch_bounds__(256) void dec_step_k(
    const int* __restrict__ trg, int t,
    const u16* __restrict__ hin, const u16* __restrict__ Wt,
    const float* __restrict__ bias, float* __restrict__ cst, u16* __restrict__ hout) {
  const int tid = threadIdx.x;
  const int lane = tid & 63, wv = tid >> 6;
  const int l15 = lane & 15, quad = lane >> 4, kq = quad * 8;
  const int hc0 = blockIdx.x * 16;
  const int Mb = (wv & 1) * 32;
  const int Ng = wv >> 1;
  __shared__ float glds[64][65];
  f32x4 acc[2][2] = {{{0.f, 0.f, 0.f, 0.f}, {0.f, 0.f, 0.f, 0.f}},
                     {{0.f, 0.f, 0.f, 0.f}, {0.f, 0.f, 0.f, 0.f}}};
  const u16* wr0 = Wt + (size_t)((Ng * 2 + 0) * 1024 + hc0 + l15) * 1088;
  const u16* wr1 = Wt + (size_t)((Ng * 2 + 1) * 1024 + hc0 + l15) * 1088;
  const int b0 = Mb + l15, b1 = Mb + 16 + l15;
  const u16* hr0 = hin + (size_t)b0 * 1024;
  const u16* hr1 = hin + (size_t)b1 * 1024;
#pragma unroll 4
  for (int ks = 0; ks < 32; ++ks) {
    const int k = ks * 32 + kq;
    bf16x8 a0 = ldb8(hr0 + k), a1 = ldb8(hr1 + k);
    bf16x8 q0 = ldb8(wr0 + 64 + k), q1 = ldb8(wr1 + 64 + k);
    acc[0][0] = MFMA16(a0, q0, acc[0][0]);
    acc[0][1] = MFMA16(a0, q1, acc[0][1]);
    acc[1][0] = MFMA16(a1, q0, acc[1][0]);
    acc[1][1] = MFMA16(a1, q1, acc[1][1]);
  }
#pragma unroll
  for (int mt = 0; mt < 2; ++mt)
#pragma unroll
    for (int nt = 0; nt < 2; ++nt)
#pragma unroll
      for (int r = 0; r < 4; ++r)
        glds[Ng * 32 + nt * 16 + l15][Mb + mt * 16 + quad * 4 + r] = acc[mt][nt][r];
  __syncthreads();
  const int hcl = tid & 15, bg = tid >> 4;
  const int hc = hc0 + hcl;
  const float bi = bias[hc], bf_ = bias[1024 + hc], bgg = bias[2048 + hc], bo = bias[3072 + hc];
#pragma unroll
  for (int r = 0; r < 4; ++r) {
    const int b = bg * 4 + r;
    const int tok = trg[b * 512 + t];
    const float gi = glds[hcl][b] + bi + bf2f(Wt[(size_t)(hc)*1088 + tok]);
    const float gf = glds[16 + hcl][b] + bf_ + bf2f(Wt[(size_t)(1024 + hc) * 1088 + tok]);
    const float gg = glds[32 + hcl][b] + bgg + bf2f(Wt[(size_t)(2048 + hc) * 1088 + tok]);
    const float go = glds[48 + hcl][b] + bo + bf2f(Wt[(size_t)(3072 + hc) * 1088 + tok]);
    const float i_ = sigmoid_(gi), f_ = sigmoid_(gf), g_ = tanh_(gg), o_ = sigmoid_(go);
    const size_t ix = (size_t)b * 1024 + hc;
    const float cn = f_ * cst[ix] + i_ * g_;
    cst[ix] = cn;
    hout[ix] = f2bf_rne(o_ * tanh_(cn));
  }
}

// ---------- final FC over all 32768 (t,b) rows ----------
__global__ __launch_bounds__(256) void fc_k(const u16* __restrict__ hrows,
                                            const u16* __restrict__ Wt,
                                            const float* __restrict__ fcb,
                                            float* __restrict__ out) {
  const int tid = threadIdx.x, lane = tid & 63, wv = tid >> 6;
  const int l15 = lane & 15, quad = lane >> 4, kq = quad * 8;
  const int r0 = blockIdx.x * 64 + wv * 16;
  const u16* ar = hrows + (size_t)(r0 + l15) * 1024;
  const u16* br0 = Wt + (size_t)(0 * 16 + l15) * 1024;
  const u16* br1 = Wt + (size_t)(1 * 16 + l15) * 1024;
  const u16* br2 = Wt + (size_t)(2 * 16 + l15) * 1024;
  const u16* br3 = Wt + (size_t)(3 * 16 + l15) * 1024;
  f32x4 acc[4] = {{0.f, 0.f, 0.f, 0.f}, {0.f, 0.f, 0.f, 0.f},
                  {0.f, 0.f, 0.f, 0.f}, {0.f, 0.f, 0.f, 0.f}};
#pragma unroll 4
  for (int ks = 0; ks < 32; ++ks) {
    const int k = ks * 32 + kq;
    bf16x8 a = ldb8(ar + k);
    acc[0] = MFMA16(a, ldb8(br0 + k), acc[0]);
    acc[1] = MFMA16(a, ldb8(br1 + k), acc[1]);
    acc[2] = MFMA16(a, ldb8(br2 + k), acc[2]);
    acc[3] = MFMA16(a, ldb8(br3 + k), acc[3]);
  }
#pragma unroll
  for (int nt = 0; nt < 4; ++nt) {
    const int tag = nt * 16 + l15;
    const float bb = fcb[tag];
#pragma unroll
    for (int r = 0; r < 4; ++r) {
      const int rr = r0 + quad * 4 + r;
      const int tt = rr >> 6, b = rr & 63;
      out[(size_t)b * 32768 + (size_t)tt * 64 + tag] = acc[nt][r] + bb;
    }
  }
}

// ---------- launch ----------
extern "C" void kernel_launch(void* const* d_in, const int* in_sizes, int n_in,
                              void* d_out, int out_size, void* d_ws, size_t ws_size,
                              hipStream_t stream) {
  const int* src = (const int*)d_in[0];
  const int* trg = (const int*)d_in[1];
  const float* emb = (const float*)d_in[2];
  const float* encW = (const float*)d_in[3];
  const float* encB = (const float*)d_in[4];
  const float* decW = (const float*)d_in[5];
  const float* decB = (const float*)d_in[6];
  const float* fcW = (const float*)d_in[7];
  const float* fcB = (const float*)d_in[8];
  float* out = (float*)d_out;

  // ws layout — identical to rounds 1-2 (proven to fit)
  const size_t OFF_WTE = 0;          // 12,582,912
  const size_t OFF_WTD = 12582912;   //  8,912,896
  const size_t OFF_WTF = 21495808;   //    131,072
  const size_t OFF_HA = 21626880;    //    131,072
  const size_t OFF_HB2 = 21757952;   //    131,072
  const size_t OFF_C = 21889024;     //    262,144 (flags | fallback c-state)
  const size_t OFF_HALL = 22151168;  // 67,239,936
  const size_t NEEDED = 89391104;
  if (ws_size < NEEDED) return;

  char* w = (char*)d_ws;
  u16* WtE = (u16*)(w + OFF_WTE);
  u16* WtD = (u16*)(w + OFF_WTD);
  u16* WtF = (u16*)(w + OFF_WTF);
  u16* hA = (u16*)(w + OFF_HA);
  u16* hB = (u16*)(w + OFF_HB2);
  unsigned* flags = (unsigned*)(w + OFF_C);
  float* cs = (float*)(w + OFF_C);  // fallback only (aliases flags; paths exclusive)
  u16* HB = (u16*)(w + OFF_HALL);

  hipMemsetAsync(hA, 0, 131072, stream);
  hipMemsetAsync((void*)flags, 0, 262144, stream);  // flags=0 (also zeroes fallback c-state)

  transpose_cvt<<<dim3(128, 48), 256, 0, stream>>>(encW, WtE, 1536, 4096);
  transpose_cvt<<<dim3(128, 34), 256, 0, stream>>>(decW, WtD, 1088, 4096);
  transpose_cvt<<<dim3(2, 32), 256, 0, stream>>>(fcW, WtF, 1024, 64);

  void* args[] = {(void*)&emb, (void*)&src, (void*)&trg, (void*)&WtE, (void*)&WtD,
                  (void*)&encB, (void*)&decB, (void*)&hA, (void*)&hB, (void*)&HB,
                  (void*)&flags};
  hipError_t e = hipLaunchCooperativeKernel((const void*)rnn_persist, dim3(256), dim3(256),
                                            args, 0, stream);
  if (e != hipSuccess) {
    // fallback: proven round-1 per-step path
    for (int t = 0; t < 512; ++t) {
      const u16* hin = (t & 1) ? hB : hA;
      u16* hout = (t == 511) ? HB : ((t & 1) ? hA : hB);
      enc_step_k<<<64, 256, 0, stream>>>(emb, src, t, hin, WtE, encB, cs, hout);
    }
    for (int t = 0; t < 512; ++t) {
      dec_step_k<<<64, 256, 0, stream>>>(trg, t, HB + (size_t)t * 65536, WtD, decB, cs,
                                         HB + (size_t)(t + 1) * 65536);
    }
  }
  fc_k<<<512, 256, 0, stream>>>(HB + 65536, WtF, fcB, out);
}

// Round 4
// 7442.339 us; speedup vs baseline: 3.5809x; 2.0545x over previous
//
#include <hip/hip_runtime.h>

typedef unsigned short u16;
typedef unsigned long long u64;
typedef short bf16x8 __attribute__((ext_vector_type(8)));
typedef float f32x4 __attribute__((ext_vector_type(4)));
typedef bf16x8 bf16x8_a __attribute__((may_alias));
typedef float f4 __attribute__((ext_vector_type(4)));
typedef f4 f4a __attribute__((may_alias));
typedef u64 u64_a __attribute__((may_alias));

#define MFMA16(a, b, c) __builtin_amdgcn_mfma_f32_16x16x32_bf16((a), (b), (c), 0, 0, 0)

#define AGLD(p) __hip_atomic_load((p), __ATOMIC_RELAXED, __HIP_MEMORY_SCOPE_AGENT)
#define AGST(p, v) __hip_atomic_store((p), (v), __ATOMIC_RELAXED, __HIP_MEMORY_SCOPE_AGENT)

// ---------- helpers ----------
__device__ __forceinline__ u16 f2bf_rne(float x) {
  unsigned u = __float_as_uint(x);
  u += 0x7FFFu + ((u >> 16) & 1u);
  return (u16)(u >> 16);
}
__device__ __forceinline__ short bfr(float x) {  // round-half-up (hot path)
  return (short)((__float_as_uint(x) + 0x8000u) >> 16);
}
__device__ __forceinline__ float bf2f(u16 h) {
  return __uint_as_float(((unsigned)h) << 16);
}
__device__ __forceinline__ float sigmoid_(float x) { return 1.0f / (1.0f + __expf(-x)); }
__device__ __forceinline__ float tanh_(float x) {
  x = fminf(8.0f, fmaxf(-8.0f, x));
  float e = __expf(2.0f * x);
  return (e - 1.0f) / (e + 1.0f);
}
__device__ __forceinline__ bf16x8 ldb8(const u16* p) { return *(const bf16x8_a*)p; }
__device__ __forceinline__ bf16x8 cvt8(const float* p) {
  f4 lo = *(const f4a*)p;
  f4 hi = *(const f4a*)(p + 4);
  bf16x8 v;
  v[0] = bfr(lo[0]); v[1] = bfr(lo[1]); v[2] = bfr(lo[2]); v[3] = bfr(lo[3]);
  v[4] = bfr(hi[0]); v[5] = bfr(hi[1]); v[6] = bfr(hi[2]); v[7] = bfr(hi[3]);
  return v;
}
union U16B {
  u64 q[2];
  bf16x8 v;
};
__device__ __forceinline__ bf16x8 mk8(u64 lo, u64 hi) {
  U16B u;
  u.q[0] = lo;
  u.q[1] = hi;
  return u.v;
}
// chunked-h A-fragment: h[chunk][row] u64; k = 32*ks + quad*8 + j -> chunks 8ks+2q, +1
__device__ __forceinline__ bf16x8 ld_chunk(const u64* hb, int ks, int quad, int row) {
  const int c0 = ks * 512 + (quad << 7) + row;
  return mk8(((const u64_a*)hb)[c0], ((const u64_a*)hb)[c0 + 64]);
}

// ---------- transpose + f32->bf16: out[c][k] = in[k][c] ----------
__global__ __launch_bounds__(256) void transpose_cvt(const float* __restrict__ in,
                                                     u16* __restrict__ out, int R, int C) {
  __shared__ float tile[32][33];
  const int tx = threadIdx.x & 31, ty = threadIdx.x >> 5;
  const int c0 = blockIdx.x * 32, r0 = blockIdx.y * 32;
#pragma unroll
  for (int i = 0; i < 32; i += 8)
    tile[ty + i][tx] = in[(size_t)(r0 + ty + i) * C + (c0 + tx)];
  __syncthreads();
#pragma unroll
  for (int i = 0; i < 32; i += 8)
    out[(size_t)(c0 + ty + i) * R + (r0 + tx)] = f2bf_rne(tile[tx][ty + i]);
}

// ==================== persistent cooperative RNN kernel ====================
// 256 WGs x 256 thr. WG owns h-cols hc0=wg*4..+3 (=chunk wg), all 4 gates.
// h buffers are CHUNKED: u64 h[256][64] (chunk-major, full-line stores).
// Publish = 512B contiguous store + s_waitcnt vmcnt(0) + relaxed flag store
// (no buffer_wbl2: every global store in this kernel is sc1 write-through).
__global__ __launch_bounds__(256, 1) void rnn_persist(
    const float* __restrict__ emb, const int* __restrict__ src, const int* __restrict__ trg,
    const u16* __restrict__ WtE, const u16* __restrict__ WtD,
    const float* __restrict__ encB, const float* __restrict__ decB,
    u64* __restrict__ hA, u64* __restrict__ hB, u64* __restrict__ HB,
    unsigned* __restrict__ flags) {
  constexpr int LDSP = 1544;
  __shared__ u16 ldsW[16 * LDSP];  // 49.4 KB
  __shared__ float glds[16][68];
  __shared__ u16 hlds[64][4];

  const int tid = threadIdx.x;
  const int lane = tid & 63, wv = tid >> 6;
  const int l15 = lane & 15, quad = lane >> 4, kq = quad * 8;
  const int Mb = wv * 16;
  const int wg = blockIdx.x;
  const int hc0 = wg * 4;
  const int eb = tid >> 2, ehc = tid & 3;
  const int arow = Mb + l15;

  // stage encoder weights: LDS row c=g*4+j <- WtE col g*1024+hc0+j
  for (int i = tid; i < 16 * 192; i += 256) {
    const int c = i / 192, ch = i % 192;
    const int g = c >> 2, j = c & 3;
    *(bf16x8_a*)&ldsW[c * LDSP + ch * 8] =
        ldb8(WtE + (size_t)(g * 1024 + hc0 + j) * 1536 + ch * 8);
  }
  float bi = encB[hc0 + ehc], bf_ = encB[1024 + hc0 + ehc],
        bg_ = encB[2048 + hc0 + ehc], bo_ = encB[3072 + hc0 + ehc];
  float cstate = 0.0f;
  __syncthreads();

  f32x4 acc[4];
  acc[0] = (f32x4){0.f, 0.f, 0.f, 0.f};
  acc[1] = acc[0]; acc[2] = acc[0]; acc[3] = acc[0];
  {  // x_gemm(t=0) prologue
    const float* er = emb + (size_t)src[arow * 512 + 0] * 512 + kq;
    const u16* wx = &ldsW[l15 * LDSP + kq];
#pragma unroll
    for (int i = 0; i < 16; ++i)
      acc[i & 3] = MFMA16(cvt8(er + i * 32), ldb8(wx + i * 32), acc[i & 3]);
  }

  // ==================== encoder: 512 steps ====================
  for (int t = 0; t < 512; ++t) {
    const unsigned ep = (unsigned)t;
    // ---- wave-0-only poll: lane checks 4 flags; exit when all 256 >= ep
    if (wv == 0) {
      const unsigned* fp = flags + (lane << 2);
      for (;;) {
        unsigned m0 = AGLD(fp + 0), m1 = AGLD(fp + 1);
        unsigned m2 = AGLD(fp + 2), m3 = AGLD(fp + 3);
        unsigned a_ = m0 < m1 ? m0 : m1, b_ = m2 < m3 ? m2 : m3;
        unsigned mn = a_ < b_ ? a_ : b_;
        if (__all((int)(mn >= ep))) break;
        __builtin_amdgcn_s_sleep(1);
      }
    }
    __syncthreads();
    __builtin_amdgcn_fence(__ATOMIC_ACQUIRE, "workgroup");

    const u64* hin = (t & 1) ? hB : hA;
    u64* hout = (t == 511) ? HB : ((t & 1) ? hA : hB);

    // ---- prefetch ALL h A-fragments (chunked layout), then MFMA
    u64 qa[64];
#pragma unroll
    for (int ks = 0; ks < 32; ++ks) {
      const int c0 = ks * 512 + (quad << 7) + arow;
      qa[2 * ks] = AGLD(hin + c0);
      qa[2 * ks + 1] = AGLD(hin + c0 + 64);
    }
    const u16* wl = &ldsW[l15 * LDSP + 512 + kq];
#pragma unroll
    for (int i = 0; i < 32; ++i)
      acc[i & 3] = MFMA16(mk8(qa[2 * i], qa[2 * i + 1]), ldb8(wl + i * 32), acc[i & 3]);

    f32x4 asum = (acc[0] + acc[1]) + (acc[2] + acc[3]);
#pragma unroll
    for (int r = 0; r < 4; ++r) glds[l15][Mb + quad * 4 + r] = asum[r];
    __syncthreads();

    {  // LSTM cell: thread -> (eb, ehc)
      const float gi = glds[ehc][eb] + bi;
      const float gf = glds[4 + ehc][eb] + bf_;
      const float gg = glds[8 + ehc][eb] + bg_;
      const float go = glds[12 + ehc][eb] + bo_;
      const float iv = sigmoid_(gi), fv = sigmoid_(gf), gv = tanh_(gg), ov = sigmoid_(go);
      cstate = fv * cstate + iv * gv;
      hlds[eb][ehc] = f2bf_rne(ov * tanh_(cstate));
    }
    __syncthreads();
    // ---- publish: one contiguous 512B block + drain + relaxed flag store
    if (tid < 64) {
      AGST(hout + (wg << 6) + tid, *(const u64*)&hlds[tid][0]);
      asm volatile("s_waitcnt vmcnt(0)" ::: "memory");
      if (tid == 0) AGST(&flags[wg], ep + 1);
    }

    // ---- overlap barrier window with next step's x-phase (no h dependency)
    acc[0] = (f32x4){0.f, 0.f, 0.f, 0.f};
    acc[1] = acc[0]; acc[2] = acc[0]; acc[3] = acc[0];
    if (t < 511) {
      const float* er = emb + (size_t)src[arow * 512 + (t + 1)] * 512 + kq;
      const u16* wx = &ldsW[l15 * LDSP + kq];
#pragma unroll
      for (int i = 0; i < 16; ++i)
        acc[i & 3] = MFMA16(cvt8(er + i * 32), ldb8(wx + i * 32), acc[i & 3]);
    }
  }

  // ---- swap to decoder weights + biases
  for (int i = tid; i < 16 * 136; i += 256) {
    const int c = i / 136, ch = i % 136;
    const int g = c >> 2, j = c & 3;
    *(bf16x8_a*)&ldsW[c * LDSP + ch * 8] =
        ldb8(WtD + (size_t)(g * 1024 + hc0 + j) * 1088 + ch * 8);
  }
  bi = decB[hc0 + ehc]; bf_ = decB[1024 + hc0 + ehc];
  bg_ = decB[2048 + hc0 + ehc]; bo_ = decB[3072 + hc0 + ehc];
  __syncthreads();

  // ==================== decoder: 512 steps ====================
  for (int t = 0; t < 512; ++t) {
    const unsigned ep = (unsigned)(512 + t);
    if (wv == 0) {
      const unsigned* fp = flags + (lane << 2);
      for (;;) {
        unsigned m0 = AGLD(fp + 0), m1 = AGLD(fp + 1);
        unsigned m2 = AGLD(fp + 2), m3 = AGLD(fp + 3);
        unsigned a_ = m0 < m1 ? m0 : m1, b_ = m2 < m3 ? m2 : m3;
        unsigned mn = a_ < b_ ? a_ : b_;
        if (__all((int)(mn >= ep))) break;
        __builtin_amdgcn_s_sleep(1);
      }
    }
    __syncthreads();
    __builtin_amdgcn_fence(__ATOMIC_ACQUIRE, "workgroup");

    const u64* hin = HB + (size_t)t * 16384;
    u64* hout = HB + (size_t)(t + 1) * 16384;

    u64 qa[64];
#pragma unroll
    for (int ks = 0; ks < 32; ++ks) {
      const int c0 = ks * 512 + (quad << 7) + arow;
      qa[2 * ks] = AGLD(hin + c0);
      qa[2 * ks + 1] = AGLD(hin + c0 + 64);
    }
    acc[0] = (f32x4){0.f, 0.f, 0.f, 0.f};
    acc[1] = acc[0]; acc[2] = acc[0]; acc[3] = acc[0];
    const u16* wl = &ldsW[l15 * LDSP + 64 + kq];
#pragma unroll
    for (int i = 0; i < 32; ++i)
      acc[i & 3] = MFMA16(mk8(qa[2 * i], qa[2 * i + 1]), ldb8(wl + i * 32), acc[i & 3]);

    f32x4 asum = (acc[0] + acc[1]) + (acc[2] + acc[3]);
#pragma unroll
    for (int r = 0; r < 4; ++r) glds[l15][Mb + quad * 4 + r] = asum[r];
    __syncthreads();

    {  // cell + one-hot gather from LDS weights (z row = trg token)
      const int tok = trg[eb * 512 + t];
      const float gi = glds[ehc][eb] + bi + bf2f(ldsW[(0 + ehc) * LDSP + tok]);
      const float gf = glds[4 + ehc][eb] + bf_ + bf2f(ldsW[(4 + ehc) * LDSP + tok]);
      const float gg = glds[8 + ehc][eb] + bg_ + bf2f(ldsW[(8 + ehc) * LDSP + tok]);
      const float go = glds[12 + ehc][eb] + bo_ + bf2f(ldsW[(12 + ehc) * LDSP + tok]);
      const float iv = sigmoid_(gi), fv = sigmoid_(gf), gv = tanh_(gg), ov = sigmoid_(go);
      cstate = fv * cstate + iv * gv;
      hlds[eb][ehc] = f2bf_rne(ov * tanh_(cstate));
    }
    __syncthreads();
    if (tid < 64) {
      AGST(hout + (wg << 6) + tid, *(const u64*)&hlds[tid][0]);
      asm volatile("s_waitcnt vmcnt(0)" ::: "memory");
      if (tid == 0) AGST(&flags[wg], ep + 1);
    }
  }
}

// ==================== fallback per-step kernels (chunked h layout) ====================
__global__ __launch_bounds__(256) void enc_step_k(
    const float* __restrict__ emb, const int* __restrict__ src, int t,
    const u64* __restrict__ hin, const u16* __restrict__ Wt,
    const float* __restrict__ bias, float* __restrict__ cst, u16* __restrict__ hout) {
  const int tid = threadIdx.x;
  const int lane = tid & 63, wv = tid >> 6;
  const int l15 = lane & 15, quad = lane >> 4, kq = quad * 8;
  const int hc0 = blockIdx.x * 16;
  const int Mb = (wv & 1) * 32;
  const int Ng = wv >> 1;
  __shared__ float glds[64][65];
  f32x4 acc[2][2] = {{{0.f, 0.f, 0.f, 0.f}, {0.f, 0.f, 0.f, 0.f}},
                     {{0.f, 0.f, 0.f, 0.f}, {0.f, 0.f, 0.f, 0.f}}};
  const u16* wr0 = Wt + (size_t)((Ng * 2 + 0) * 1024 + hc0 + l15) * 1536;
  const u16* wr1 = Wt + (size_t)((Ng * 2 + 1) * 1024 + hc0 + l15) * 1536;
  const int b0 = Mb + l15, b1 = Mb + 16 + l15;
  const float* er0 = emb + (size_t)src[b0 * 512 + t] * 512;
  const float* er1 = emb + (size_t)src[b1 * 512 + t] * 512;
#pragma unroll 4
  for (int ks = 0; ks < 16; ++ks) {
    const int k = ks * 32 + kq;
    bf16x8 a0 = cvt8(er0 + k), a1 = cvt8(er1 + k);
    bf16x8 q0 = ldb8(wr0 + k), q1 = ldb8(wr1 + k);
    acc[0][0] = MFMA16(a0, q0, acc[0][0]);
    acc[0][1] = MFMA16(a0, q1, acc[0][1]);
    acc[1][0] = MFMA16(a1, q0, acc[1][0]);
    acc[1][1] = MFMA16(a1, q1, acc[1][1]);
  }
#pragma unroll 4
  for (int ks = 0; ks < 32; ++ks) {
    const int k = ks * 32 + kq;
    bf16x8 a0 = ld_chunk(hin, ks, quad, b0);
    bf16x8 a1 = ld_chunk(hin, ks, quad, b1);
    bf16x8 q0 = ldb8(wr0 + 512 + k), q1 = ldb8(wr1 + 512 + k);
    acc[0][0] = MFMA16(a0, q0, acc[0][0]);
    acc[0][1] = MFMA16(a0, q1, acc[0][1]);
    acc[1][0] = MFMA16(a1, q0, acc[1][0]);
    acc[1][1] = MFMA16(a1, q1, acc[1][1]);
  }
#pragma unroll
  for (int mt = 0; mt < 2; ++mt)
#pragma unroll
    for (int nt = 0; nt < 2; ++nt)
#pragma unroll
      for (int r = 0; r < 4; ++r)
        glds[Ng * 32 + nt * 16 + l15][Mb + mt * 16 + quad * 4 + r] = acc[mt][nt][r];
  __syncthreads();
  const int hcl = tid & 15, bg = tid >> 4;
  const int hc = hc0 + hcl;
  const float bi = bias[hc], bf_ = bias[1024 + hc], bgg = bias[2048 + hc], bo = bias[3072 + hc];
#pragma unroll
  for (int r = 0; r < 4; ++r) {
    const int b = bg * 4 + r;
    const float gi = glds[hcl][b] + bi;
    const float gf = glds[16 + hcl][b] + bf_;
    const float gg = glds[32 + hcl][b] + bgg;
    const float go = glds[48 + hcl][b] + bo;
    const float i_ = sigmoid_(gi), f_ = sigmoid_(gf), g_ = tanh_(gg), o_ = sigmoid_(go);
    const float cn = f_ * cst[(size_t)b * 1024 + hc] + i_ * g_;
    cst[(size_t)b * 1024 + hc] = cn;
    hout[(hc >> 2) * 256 + b * 4 + (hc & 3)] = f2bf_rne(o_ * tanh_(cn));
  }
}

__global__ __launch_bounds__(256) void dec_step_k(
    const int* __restrict__ trg, int t,
    const u64* __restrict__ hin, const u16* __restrict__ Wt,
    const float* __restrict__ bias, float* __restrict__ cst, u16* __restrict__ hout) {
  const int tid = threadIdx.x;
  const int lane = tid & 63, wv = tid >> 6;
  const int l15 = lane & 15, quad = lane >> 4, kq = quad * 8;
  const int hc0 = blockIdx.x * 16;
  const int Mb = (wv & 1) * 32;
  const int Ng = wv >> 1;
  __shared__ float glds[64][65];
  f32x4 acc[2][2] = {{{0.f, 0.f, 0.f, 0.f}, {0.f, 0.f, 0.f, 0.f}},
                     {{0.f, 0.f, 0.f, 0.f}, {0.f, 0.f, 0.f, 0.f}}};
  const u16* wr0 = Wt + (size_t)((Ng * 2 + 0) * 1024 + hc0 + l15) * 1088;
  const u16* wr1 = Wt + (size_t)((Ng * 2 + 1) * 1024 + hc0 + l15) * 1088;
  const int b0 = Mb + l15, b1 = Mb + 16 + l15;
#pragma unroll 4
  for (int ks = 0; ks < 32; ++ks) {
    const int k = ks * 32 + kq;
    bf16x8 a0 = ld_chunk(hin, ks, quad, b0);
    bf16x8 a1 = ld_chunk(hin, ks, quad, b1);
    bf16x8 q0 = ldb8(wr0 + 64 + k), q1 = ldb8(wr1 + 64 + k);
    acc[0][0] = MFMA16(a0, q0, acc[0][0]);
    acc[0][1] = MFMA16(a0, q1, acc[0][1]);
    acc[1][0] = MFMA16(a1, q0, acc[1][0]);
    acc[1][1] = MFMA16(a1, q1, acc[1][1]);
  }
#pragma unroll
  for (int mt = 0; mt < 2; ++mt)
#pragma unroll
    for (int nt = 0; nt < 2; ++nt)
#pragma unroll
      for (int r = 0; r < 4; ++r)
        glds[Ng * 32 + nt * 16 + l15][Mb + mt * 16 + quad * 4 + r] = acc[mt][nt][r];
  __syncthreads();
  const int hcl = tid & 15, bg = tid >> 4;
  const int hc = hc0 + hcl;
  const float bi = bias[hc], bf_ = bias[1024 + hc], bgg = bias[2048 + hc], bo = bias[3072 + hc];
#pragma unroll
  for (int r = 0; r < 4; ++r) {
    const int b = bg * 4 + r;
    const int tok = trg[b * 512 + t];
    const float gi = glds[hcl][b] + bi + bf2f(Wt[(size_t)(hc)*1088 + tok]);
    const float gf = glds[16 + hcl][b] + bf_ + bf2f(Wt[(size_t)(1024 + hc) * 1088 + tok]);
    const float gg = glds[32 + hcl][b] + bgg + bf2f(Wt[(size_t)(2048 + hc) * 1088 + tok]);
    const float go = glds[48 + hcl][b] + bo + bf2f(Wt[(size_t)(3072 + hc) * 1088 + tok]);
    const float i_ = sigmoid_(gi), f_ = sigmoid_(gf), g_ = tanh_(gg), o_ = sigmoid_(go);
    const float cn = f_ * cst[(size_t)b * 1024 + hc] + i_ * g_;
    cst[(size_t)b * 1024 + hc] = cn;
    hout[(hc >> 2) * 256 + b * 4 + (hc & 3)] = f2bf_rne(o_ * tanh_(cn));
  }
}

// ---------- final FC over all 32768 (t,b) rows, chunked h input ----------
__global__ __launch_bounds__(256) void fc_k(const u64* __restrict__ HBc,
                                            const u16* __restrict__ Wt,
                                            const float* __restrict__ fcb,
                                            float* __restrict__ out) {
  const int tid = threadIdx.x, lane = tid & 63, wv = tid >> 6;
  const int l15 = lane & 15, quad = lane >> 4, kq = quad * 8;
  const int r0 = blockIdx.x * 64 + wv * 16;
  const int t = r0 >> 6;                 // fixed per wave (r0 multiple of 16)
  const int b = (r0 & 63) + l15;         // A-row within the step
  const u64* ab = HBc + (size_t)(t + 1) * 16384;
  const u16* br0 = Wt + (size_t)(0 * 16 + l15) * 1024;
  const u16* br1 = Wt + (size_t)(1 * 16 + l15) * 1024;
  const u16* br2 = Wt + (size_t)(2 * 16 + l15) * 1024;
  const u16* br3 = Wt + (size_t)(3 * 16 + l15) * 1024;
  f32x4 acc[4] = {{0.f, 0.f, 0.f, 0.f}, {0.f, 0.f, 0.f, 0.f},
                  {0.f, 0.f, 0.f, 0.f}, {0.f, 0.f, 0.f, 0.f}};
#pragma unroll 4
  for (int ks = 0; ks < 32; ++ks) {
    const int k = ks * 32 + kq;
    bf16x8 a = ld_chunk(ab, ks, quad, b);
    acc[0] = MFMA16(a, ldb8(br0 + k), acc[0]);
    acc[1] = MFMA16(a, ldb8(br1 + k), acc[1]);
    acc[2] = MFMA16(a, ldb8(br2 + k), acc[2]);
    acc[3] = MFMA16(a, ldb8(br3 + k), acc[3]);
  }
#pragma unroll
  for (int nt = 0; nt < 4; ++nt) {
    const int tag = nt * 16 + l15;
    const float bb = fcb[tag];
#pragma unroll
    for (int r = 0; r < 4; ++r) {
      const int rr = r0 + quad * 4 + r;
      const int tt = rr >> 6, bo_ = rr & 63;
      out[(size_t)bo_ * 32768 + (size_t)tt * 64 + tag] = acc[nt][r] + bb;
    }
  }
}

// ---------- launch ----------
extern "C" void kernel_launch(void* const* d_in, const int* in_sizes, int n_in,
                              void* d_out, int out_size, void* d_ws, size_t ws_size,
                              hipStream_t stream) {
  const int* src = (const int*)d_in[0];
  const int* trg = (const int*)d_in[1];
  const float* emb = (const float*)d_in[2];
  const float* encW = (const float*)d_in[3];
  const float* encB = (const float*)d_in[4];
  const float* decW = (const float*)d_in[5];
  const float* decB = (const float*)d_in[6];
  const float* fcW = (const float*)d_in[7];
  const float* fcB = (const float*)d_in[8];
  float* out = (float*)d_out;

  // ws layout — identical offsets to rounds 1-3 (proven to fit)
  const size_t OFF_WTE = 0;          // 12,582,912
  const size_t OFF_WTD = 12582912;   //  8,912,896
  const size_t OFF_WTF = 21495808;   //    131,072
  const size_t OFF_HA = 21626880;    //    131,072
  const size_t OFF_HB2 = 21757952;   //    131,072
  const size_t OFF_C = 21889024;     //    262,144 (flags | fallback c-state)
  const size_t OFF_HALL = 22151168;  // 67,239,936
  const size_t NEEDED = 89391104;
  if (ws_size < NEEDED) return;

  char* w = (char*)d_ws;
  u16* WtE = (u16*)(w + OFF_WTE);
  u16* WtD = (u16*)(w + OFF_WTD);
  u16* WtF = (u16*)(w + OFF_WTF);
  u64* hA = (u64*)(w + OFF_HA);
  u64* hB = (u64*)(w + OFF_HB2);
  unsigned* flags = (unsigned*)(w + OFF_C);
  float* cs = (float*)(w + OFF_C);  // fallback only (aliases flags; paths exclusive)
  u64* HB = (u64*)(w + OFF_HALL);   // chunked: 513 steps x 16384 u64

  hipMemsetAsync(hA, 0, 131072, stream);
  hipMemsetAsync((void*)flags, 0, 262144, stream);

  transpose_cvt<<<dim3(128, 48), 256, 0, stream>>>(encW, WtE, 1536, 4096);
  transpose_cvt<<<dim3(128, 34), 256, 0, stream>>>(decW, WtD, 1088, 4096);
  transpose_cvt<<<dim3(2, 32), 256, 0, stream>>>(fcW, WtF, 1024, 64);

  void* args[] = {(void*)&emb, (void*)&src, (void*)&trg, (void*)&WtE, (void*)&WtD,
                  (void*)&encB, (void*)&decB, (void*)&hA, (void*)&hB, (void*)&HB,
                  (void*)&flags};
  hipError_t e = hipLaunchCooperativeKernel((const void*)rnn_persist, dim3(256), dim3(256),
                                            args, 0, stream);
  if (e != hipSuccess) {
    // fallback: per-step path (chunked h layout)
    for (int t = 0; t < 512; ++t) {
      const u64* hin = (t & 1) ? hB : hA;
      u64* hout = (t == 511) ? HB : ((t & 1) ? hA : hB);
      enc_step_k<<<64, 256, 0, stream>>>(emb, src, t, hin, WtE, encB, cs, (u16*)hout);
    }
    for (int t = 0; t < 512; ++t) {
      dec_step_k<<<64, 256, 0, stream>>>(trg, t, HB + (size_t)t * 16384, WtD, decB, cs,
                                         (u16*)(HB + (size_t)(t + 1) * 16384));
    }
  }
  fc_k<<<512, 256, 0, stream>>>(HB, WtF, fcB, out);
}